// Round 4
// baseline (368.964 us; speedup 1.0000x reference)
//
#include <hip/hip_runtime.h>

// ---------------------------------------------------------------------------
// LabelSimilarity: match[b,l] = max(-1, max_{s,v} cos(embed[s,b,:], label[l,v,:]))
// S=256 B=128 D=768 ; L=200 V=8 ; out [128,200] fp32
//
// R11: revert to the R7 main loop (known 147us gemm; R8-R10's counted-vmcnt
// pipeline regressed: 48KB LDS cut resident blocks 5->3/CU, occupancy
// 30->21.7%, gemm 164us -- TLP across 5 blocks was already hiding what the
// pipeline tried to hide, at lower cost). NEW: the scratch round-trip
// (27MB write + 27MB read + reduce1 launch) is replaced by exact atomicMax
// folding over s: monotone float->uint key (x>=0 ? u|0x80000000 : ~u) makes
// fp max order-independent; partial = 13x2048 u32 (104KB, L2-resident),
// initialized to key(-1.0)=0x407FFFFF in normalize_all (free max(-1,.)
// clamp). Gemm epilogue: shuffle-reduce over v then 2048 fire-and-forget
// atomics/block; LDS-compact pass + 2 epilogue barriers deleted. decode
// kernel (104 blocks) replaces reduce1+reduce2.
// XCD clustering (R6), XOR swizzles (R2), merged normalize (R7) kept.
// ---------------------------------------------------------------------------

typedef __bf16 bf16x8 __attribute__((ext_vector_type(8)));
typedef float  f32x4  __attribute__((ext_vector_type(4)));

#define GLD16(gp, lp) __builtin_amdgcn_global_load_lds(                        \
    (__attribute__((address_space(1))) void*)(gp),                             \
    (__attribute__((address_space(3))) void*)(lp), 16, 0, 0)

__device__ __forceinline__ unsigned short f32_to_bf16_rne(float x) {
  unsigned u = __float_as_uint(x);
  u += 0x7fffu + ((u >> 16) & 1u);
  return (unsigned short)(u >> 16);
}

// Monotone order-preserving float<->uint key (no NaN in this problem).
__device__ __forceinline__ unsigned fkey(float x) {
  unsigned u = __float_as_uint(x);
  return (u & 0x80000000u) ? ~u : (u | 0x80000000u);
}
__device__ __forceinline__ float fdekey(unsigned k) {
  unsigned u = (k & 0x80000000u) ? (k ^ 0x80000000u) : ~k;
  return __uint_as_float(u);
}
#define KEY_NEG1 0x407FFFFFu   // fkey(-1.0f): ~0xBF800000

// One wave per row, both tensors in one launch:
// rows [0,32768) -> embed->Ap ; rows [32768, 32768+1664) -> label->Bp
// (label rows >= 1600 are zero pad). Also initializes partial[] keys.
__global__ void __launch_bounds__(256) normalize_all(
    const float* __restrict__ embed, const float* __restrict__ label,
    unsigned short* __restrict__ Ap, unsigned short* __restrict__ Bp,
    unsigned* __restrict__ P) {
  int gid = blockIdx.x * 256 + threadIdx.x;
  if (gid < 13 * 2048) P[gid] = KEY_NEG1;   // init before gemm launch (stream-ordered)

  int row  = blockIdx.x * 4 + (threadIdx.x >> 6);
  int lane = threadIdx.x & 63;
  const float* src;
  unsigned short* dstp;
  if (row < 32768) {
    src  = embed + (size_t)row * 768;
    dstp = Ap + (size_t)row * 768;
  } else {
    int lr = row - 32768;
    if (lr >= 1664) return;
    dstp = Bp + (size_t)lr * 768;
    if (lr >= 1600) {
      ushort4 z; z.x = z.y = z.z = z.w = 0;
      ushort4* drow = (ushort4*)dstp;
#pragma unroll
      for (int t = 0; t < 3; ++t) drow[lane + 64 * t] = z;
      return;
    }
    src = label + (size_t)lr * 768;
  }
  const float4* srow = (const float4*)src;
  ushort4* drow = (ushort4*)dstp;
  float4 v[3];
  float ss = 0.f;
#pragma unroll
  for (int t = 0; t < 3; ++t) {
    v[t] = srow[lane + 64 * t];
    ss += v[t].x * v[t].x + v[t].y * v[t].y + v[t].z * v[t].z + v[t].w * v[t].w;
  }
#pragma unroll
  for (int off = 1; off < 64; off <<= 1) ss += __shfl_xor(ss, off);
  float rinv = rsqrtf(fmaxf(ss, 1e-12f));
#pragma unroll
  for (int t = 0; t < 3; ++t) {
    ushort4 h;
    h.x = f32_to_bf16_rne(v[t].x * rinv);
    h.y = f32_to_bf16_rne(v[t].y * rinv);
    h.z = f32_to_bf16_rne(v[t].z * rinv);
    h.w = f32_to_bf16_rne(v[t].w * rinv);
    drow[lane + 64 * t] = h;
  }
}

// GEMM + per-block max over v + atomicMax fold over s. 1-D grid 3328;
// XCD-clustered. R7 main loop: 2x16KB double-buffered sets, one
// __syncthreads per K-iter, prefetch of chunk kk+1 issued right after it.
__global__ void __launch_bounds__(256) gemm_atomic_kernel(
    const unsigned short* __restrict__ Ap,   // [32768][768] bf16 (normalized)
    const unsigned short* __restrict__ Bp,   // [1664][768]  bf16 (normalized)
    unsigned* __restrict__ P) {              // [13][2048] keyed maxima
  __shared__ char smem[32768];   // set0: A[0,8K) B[8K,16K) ; set1: +16K

  const int t    = threadIdx.x;
  const int lane = t & 63;
  const int w    = t >> 6;             // wave 0..3

  // XCD-aware decode: blk -> (bx, s); the 13 A-tile sharers co-locate.
  const int blk = blockIdx.x;          // 0..3327
  const int xcd = blk & 7;
  const int idx = blk >> 3;            // 0..415
  const int bx  = idx % 13;
  const int s   = xcd * 32 + idx / 13;
  const int n0  = bx * 128;

  // staging: LDS slot == t (16B). slot (row=t>>2, cs=t&3) holds global chunk
  // cg = cs ^ ((row>>1)&3) (swizzle stays inside the row's 64B line).
  const int srow = t >> 2;
  const int cg   = (t & 3) ^ ((t >> 3) & 3);
  const char* gA = (const char*)(Ap + (size_t)(s * 128) * 768);
  const char* gB = (const char*)(Bp + (size_t)n0 * 768);
  const char* ga0 = gA + srow * 1536 + cg * 16;          // rows 0..63
  const char* ga1 = ga0 + 64 * 1536;                     // rows 64..127
  const char* gb0 = gB + srow * 1536 + cg * 16;
  const char* gb1 = gb0 + 64 * 1536;
  const int lA0 = w * 1024;            // offsets within a 16 KB set
  const int lA1 = 4096 + w * 1024;
  const int lB0 = 8192 + w * 1024;
  const int lB1 = 12288 + w * 1024;

  // wave tile: 2x2 waves, each 64x64 = 4x4 MFMA tiles of 16x16
  const int wm  = (w >> 1) * 64;
  const int wn  = (w & 1) * 64;
  const int r16 = lane & 15;
  const int swz  = (((lane >> 4) ^ ((r16 >> 1) & 3)) * 16);   // bytes
  const int aoffB = (wm + r16) * 64 + swz;          // within set's A half
  const int boffB = 8192 + (wn + r16) * 64 + swz;   // within set's B half

  f32x4 acc[4][4];
#pragma unroll
  for (int i = 0; i < 4; ++i)
#pragma unroll
    for (int j = 0; j < 4; ++j)
      acc[i][j] = (f32x4){0.f, 0.f, 0.f, 0.f};

  // prologue: stage chunk 0 into set 0
  GLD16(ga0, smem + lA0); GLD16(ga1, smem + lA1);
  GLD16(gb0, smem + lB0); GLD16(gb1, smem + lB1);
  ga0 += 64; ga1 += 64; gb0 += 64; gb1 += 64;

  for (int kk = 0; kk < 24; ++kk) {    // K = 768 = 24 * 32
    __syncthreads();                   // drains chunk-kk loads (issued 1 iter ago)
    char* const Sc = smem + (kk & 1) * 16384;        // compute set
    if (kk < 23) {                     // prefetch chunk kk+1 into other set
      char* const Sp = smem + ((kk + 1) & 1) * 16384;
      GLD16(ga0, Sp + lA0); GLD16(ga1, Sp + lA1);
      GLD16(gb0, Sp + lB0); GLD16(gb1, Sp + lB1);
      ga0 += 64; ga1 += 64; gb0 += 64; gb1 += 64;
    }
    bf16x8 af[4], bfr[4];
#pragma unroll
    for (int i = 0; i < 4; ++i)
      af[i] = *(const bf16x8*)(Sc + aoffB + i * 1024);
#pragma unroll
    for (int j = 0; j < 4; ++j)
      bfr[j] = *(const bf16x8*)(Sc + boffB + j * 1024);
#pragma unroll
    for (int i = 0; i < 4; ++i)
#pragma unroll
      for (int j = 0; j < 4; ++j)
        acc[i][j] = __builtin_amdgcn_mfma_f32_16x16x32_bf16(
            af[i], bfr[j], acc[i][j], 0, 0, 0);
  }

  // epilogue: acc is cos. C/D: col=lane&15, row=(lane>>4)*4+r.
  // max over v (col groups of 8) via shuffle; writer lanes (lane&7==0) fold
  // over s with exact keyed atomicMax into the block's bx-slice of P.
  // No LDS use, no barriers needed.
  unsigned* Pb = P + bx * 2048;
  const int rowg = lane >> 4;
  const int lbit = (lane >> 3) & 1;
  const bool writer = (lane & 7) == 0;
#pragma unroll
  for (int i = 0; i < 4; ++i) {
#pragma unroll
    for (int j = 0; j < 4; ++j) {
#pragma unroll
      for (int r = 0; r < 4; ++r) {
        float vv = acc[i][j][r];
        vv = fmaxf(vv, __shfl_xor(vv, 1));
        vv = fmaxf(vv, __shfl_xor(vv, 2));
        vv = fmaxf(vv, __shfl_xor(vv, 4));
        if (writer) {
          int b  = wm + i * 16 + rowg * 4 + r;
          int ll = (wn >> 3) + j * 2 + lbit;
          atomicMax(Pb + b * 16 + ll, fkey(vv));
        }
      }
    }
  }
}

// decode: out[b][l] = dekey(partial) (init key(-1) already applied the clamp)
__global__ void __launch_bounds__(256) decode_kernel(
    const unsigned* __restrict__ P, float* __restrict__ out) {
  int idx = blockIdx.x * 256 + threadIdx.x;   // 0 .. 26623
  if (idx >= 13 * 2048) return;
  int bx = idx >> 11;
  int e  = idx & 2047;
  int b  = e >> 4;
  int ll = e & 15;
  int l  = bx * 16 + ll;
  if (l >= 200) return;
  out[b * 200 + l] = fdekey(P[idx]);
}

// Brute-force fp32 fallback (only if ws_size is too small): one block per (b,l).
__global__ void __launch_bounds__(256) fallback_kernel(
    const float* __restrict__ embed, const float* __restrict__ label,
    float* __restrict__ out) {
  int b = blockIdx.x, l = blockIdx.y, t = threadIdx.x;
  float m = -1.0f;
  for (int p = t; p < 2048; p += 256) {
    int s = p >> 3, v = p & 7;
    const float* e = embed + (size_t)(s * 128 + b) * 768;
    const float* q = label + (size_t)(l * 8 + v) * 768;
    float dot = 0.f, ne = 0.f, nl = 0.f;
    for (int d = 0; d < 768; ++d) {
      float x = e[d], y = q[d];
      dot += x * y; ne += x * x; nl += y * y;
    }
    m = fmaxf(m, dot / fmaxf(sqrtf(ne) * sqrtf(nl), 1e-8f));
  }
  for (int off = 1; off < 64; off <<= 1) m = fmaxf(m, __shfl_xor(m, off));
  __shared__ float wmax[4];
  if ((t & 63) == 0) wmax[t >> 6] = m;
  __syncthreads();
  if (t == 0)
    out[b * 200 + l] = fmaxf(fmaxf(wmax[0], wmax[1]), fmaxf(wmax[2], wmax[3]));
}

extern "C" void kernel_launch(void* const* d_in, const int* in_sizes, int n_in,
                              void* d_out, int out_size, void* d_ws, size_t ws_size,
                              hipStream_t stream) {
  const float* embed = (const float*)d_in[0];   // [256,128,768]
  const float* label = (const float*)d_in[1];   // [200,8,768]
  float* out = (float*)d_out;                   // [128,200]

  const size_t szA = (size_t)32768 * 768 * 2;        // 50,331,648
  const size_t szB = (size_t)1664 * 768 * 2;         //  2,555,904
  const size_t szP = (size_t)13 * 2048 * 4;          //    106,496

  if (ws_size < szA + szB + szP) {
    dim3 g(128, 200);
    fallback_kernel<<<g, 256, 0, stream>>>(embed, label, out);
    return;
  }

  unsigned short* Ap = (unsigned short*)d_ws;
  unsigned short* Bp = (unsigned short*)((char*)d_ws + szA);
  unsigned* P        = (unsigned*)((char*)d_ws + szA + szB);

  normalize_all<<<8608, 256, 0, stream>>>(embed, label, Ap, Bp, P);
  gemm_atomic_kernel<<<3328, 256, 0, stream>>>(Ap, Bp, P);
  decode_kernel<<<104, 256, 0, stream>>>(P, out);
}

// Round 5
// 298.266 us; speedup vs baseline: 1.2370x; 1.2370x over previous
//
#include <hip/hip_runtime.h>

// ---------------------------------------------------------------------------
// LabelSimilarity: match[b,l] = max(-1, max_{s,v} cos(embed[s,b,:], label[l,v,:]))
// S=256 B=128 D=768 ; L=200 V=8 ; out [128,200] fp32
//
// R12: back to the R7 structure (scratch + reduce1/reduce2; R11's atomicMax
// punched through per-XCD L2 -> 104MB HBM writes, gemm 225us). NEW: N-tile
// halved, 128x64 output per block (26 bx x 256 s = 6656 blocks). Rationale
// (R7 counters + m69): VGPR=68 caps residency at 4 waves/SIMD (granule steps
// 64/128/256) and measured avg was ~2.4 blocks/CU -> ~880cyc/iter of exposed
// L2 latency at the __syncthreads drain with nothing to hide it. Smaller
// tile: LDS set 12KB (A 8KB + B 4KB), dbuf 24KB -> LDS allows 6 blocks/CU;
// acc[4][2] halves acc VGPR -> ~70 total, 4-block VGPR cap; expected ~4
// resident blocks = ~16 waves of TLP to hide the drain. A restaged 26x (was
// 13x) costs +640MB L2 traffic -- L2 is at 26% utilization, the idle pipe.
// Sync structure identical to R7 (one __syncthreads per K-iter, prefetch
// after barrier). XCD clustering (R6), XOR swizzles (R2), merged normalize
// (R7) kept. Scratch totals unchanged (26x256x1024 = 13x256x2048 floats).
// ---------------------------------------------------------------------------

typedef __bf16 bf16x8 __attribute__((ext_vector_type(8)));
typedef float  f32x4  __attribute__((ext_vector_type(4)));

#define GLD16(gp, lp) __builtin_amdgcn_global_load_lds(                        \
    (__attribute__((address_space(1))) void*)(gp),                             \
    (__attribute__((address_space(3))) void*)(lp), 16, 0, 0)

__device__ __forceinline__ unsigned short f32_to_bf16_rne(float x) {
  unsigned u = __float_as_uint(x);
  u += 0x7fffu + ((u >> 16) & 1u);
  return (unsigned short)(u >> 16);
}

// One wave per row, both tensors in one launch:
// rows [0,32768) -> embed->Ap ; rows [32768, 32768+1664) -> label->Bp
// (label rows >= 1600 are zero pad).
__global__ void __launch_bounds__(256) normalize_all(
    const float* __restrict__ embed, const float* __restrict__ label,
    unsigned short* __restrict__ Ap, unsigned short* __restrict__ Bp) {
  int row  = blockIdx.x * 4 + (threadIdx.x >> 6);
  int lane = threadIdx.x & 63;
  const float* src;
  unsigned short* dstp;
  if (row < 32768) {
    src  = embed + (size_t)row * 768;
    dstp = Ap + (size_t)row * 768;
  } else {
    int lr = row - 32768;
    if (lr >= 1664) return;
    dstp = Bp + (size_t)lr * 768;
    if (lr >= 1600) {
      ushort4 z; z.x = z.y = z.z = z.w = 0;
      ushort4* drow = (ushort4*)dstp;
#pragma unroll
      for (int t = 0; t < 3; ++t) drow[lane + 64 * t] = z;
      return;
    }
    src = label + (size_t)lr * 768;
  }
  const float4* srow = (const float4*)src;
  ushort4* drow = (ushort4*)dstp;
  float4 v[3];
  float ss = 0.f;
#pragma unroll
  for (int t = 0; t < 3; ++t) {
    v[t] = srow[lane + 64 * t];
    ss += v[t].x * v[t].x + v[t].y * v[t].y + v[t].z * v[t].z + v[t].w * v[t].w;
  }
#pragma unroll
  for (int off = 1; off < 64; off <<= 1) ss += __shfl_xor(ss, off);
  float rinv = rsqrtf(fmaxf(ss, 1e-12f));
#pragma unroll
  for (int t = 0; t < 3; ++t) {
    ushort4 h;
    h.x = f32_to_bf16_rne(v[t].x * rinv);
    h.y = f32_to_bf16_rne(v[t].y * rinv);
    h.z = f32_to_bf16_rne(v[t].z * rinv);
    h.w = f32_to_bf16_rne(v[t].w * rinv);
    drow[lane + 64 * t] = h;
  }
}

// GEMM + per-block max tile. Output tile 128(s-rows) x 64(label-cols).
// 1-D grid 6656; XCD-clustered (26 A-sharers co-located).
// Writes scratch[(bx*256+s)*1024 + b*8 + ll].
__global__ void __launch_bounds__(256) gemm_store_kernel(
    const unsigned short* __restrict__ Ap,   // [32768][768] bf16 (normalized)
    const unsigned short* __restrict__ Bp,   // [1664][768]  bf16 (normalized)
    float* __restrict__ scratch) {
  __shared__ char smem[24576];   // set0: A[0,8K) B[8K,12K) ; set1: +12K

  const int t    = threadIdx.x;
  const int lane = t & 63;
  const int w    = t >> 6;             // wave 0..3

  // XCD-aware decode: blk -> (bx, s); the 26 A-tile sharers co-locate.
  const int blk = blockIdx.x;          // 0..6655
  const int xcd = blk & 7;
  const int idx = blk >> 3;            // 0..831
  const int bx  = idx % 26;
  const int s   = xcd * 32 + idx / 26;
  const int n0  = bx * 64;

  // staging: LDS slot == t (16B). slot (row=t>>2, cs=t&3) holds global chunk
  // cg = cs ^ ((row>>1)&3) (swizzle stays inside the row's 64B line).
  const int srow = t >> 2;
  const int cg   = (t & 3) ^ ((t >> 3) & 3);
  const char* gA = (const char*)(Ap + (size_t)(s * 128) * 768);
  const char* gB = (const char*)(Bp + (size_t)n0 * 768);
  const char* ga0 = gA + srow * 1536 + cg * 16;          // A rows 0..63
  const char* ga1 = ga0 + 64 * 1536;                     // A rows 64..127
  const char* gb0 = gB + srow * 1536 + cg * 16;          // B rows 0..63
  const int lA0 = w * 1024;            // offsets within a 12 KB set
  const int lA1 = 4096 + w * 1024;
  const int lB0 = 8192 + w * 1024;     // B half: 4 KB, all 256 threads

  // wave tile: 2x2 waves, each 64(M)x32(N) = 4x2 MFMA tiles of 16x16
  const int wm  = (w >> 1) * 64;
  const int wn  = (w & 1) * 32;
  const int r16 = lane & 15;
  const int swz  = (((lane >> 4) ^ ((r16 >> 1) & 3)) * 16);   // bytes
  const int aoffB = (wm + r16) * 64 + swz;          // within set's A half
  const int boffB = 8192 + (wn + r16) * 64 + swz;   // within set's B half

  f32x4 acc[4][2];
#pragma unroll
  for (int i = 0; i < 4; ++i)
#pragma unroll
    for (int j = 0; j < 2; ++j)
      acc[i][j] = (f32x4){0.f, 0.f, 0.f, 0.f};

  // prologue: stage chunk 0 into set 0 (3 GLD16/thread: A x2, B x1)
  GLD16(ga0, smem + lA0); GLD16(ga1, smem + lA1);
  GLD16(gb0, smem + lB0);
  ga0 += 64; ga1 += 64; gb0 += 64;

  for (int kk = 0; kk < 24; ++kk) {    // K = 768 = 24 * 32
    __syncthreads();                   // drains chunk-kk loads (issued 1 iter ago)
    char* const Sc = smem + (kk & 1) * 12288;        // compute set
    if (kk < 23) {                     // prefetch chunk kk+1 into other set
      char* const Sp = smem + ((kk + 1) & 1) * 12288;
      GLD16(ga0, Sp + lA0); GLD16(ga1, Sp + lA1);
      GLD16(gb0, Sp + lB0);
      ga0 += 64; ga1 += 64; gb0 += 64;
    }
    bf16x8 af[4], bfr[2];
#pragma unroll
    for (int i = 0; i < 4; ++i)
      af[i] = *(const bf16x8*)(Sc + aoffB + i * 1024);
#pragma unroll
    for (int j = 0; j < 2; ++j)
      bfr[j] = *(const bf16x8*)(Sc + boffB + j * 1024);
#pragma unroll
    for (int i = 0; i < 4; ++i)
#pragma unroll
      for (int j = 0; j < 2; ++j)
        acc[i][j] = __builtin_amdgcn_mfma_f32_16x16x32_bf16(
            af[i], bfr[j], acc[i][j], 0, 0, 0);
  }
  __syncthreads();                     // all ds_reads done before smem reuse

  // epilogue: acc is cos. C/D: col=lane&15, row=(lane>>4)*4+r.
  // max over v (col groups of 8) via shuffle; compact via LDS (stride 9),
  // then coalesced float4 stores to the block's private scratch tile.
  float* red = (float*)smem;           // [128][9] floats = 4608 B
  const int rowg  = lane >> 4;
  const int lbit  = (lane >> 3) & 1;
  const bool writer = (lane & 7) == 0;
#pragma unroll
  for (int i = 0; i < 4; ++i) {
#pragma unroll
    for (int j = 0; j < 2; ++j) {
#pragma unroll
      for (int r = 0; r < 4; ++r) {
        float vv = acc[i][j][r];
        vv = fmaxf(vv, __shfl_xor(vv, 1));
        vv = fmaxf(vv, __shfl_xor(vv, 2));
        vv = fmaxf(vv, __shfl_xor(vv, 4));
        if (writer) {
          int b  = wm + i * 16 + rowg * 4 + r;
          int ll = (wn >> 3) + j * 2 + lbit;     // 0..7
          red[b * 9 + ll] = vv;
        }
      }
    }
  }
  __syncthreads();
  {
    const int b  = t >> 1;             // 0..127
    const int l0 = (t & 1) * 4;        // 0 or 4
    float4 p;
    p.x = red[b * 9 + l0 + 0]; p.y = red[b * 9 + l0 + 1];
    p.z = red[b * 9 + l0 + 2]; p.w = red[b * 9 + l0 + 3];
    float4* gg = (float4*)(scratch + ((size_t)(bx * 256 + s)) * 1024 + t * 4);
    gg[0] = p;
  }
}

// reduce1: block (bx, sg) folds s in [sg*8, sg*8+8) -> partial[bx][sg][1024]
__global__ void __launch_bounds__(256) reduce1_kernel(
    const float* __restrict__ scratch, float* __restrict__ partial) {
  const int t  = threadIdx.x;
  const int bx = blockIdx.x;
  const int sg = blockIdx.y;
  const float* base = scratch + ((size_t)(bx * 256 + sg * 8)) * 1024 + t * 4;
  float4 m0 = ((const float4*)base)[0];
  for (int ss = 1; ss < 8; ++ss) {
    float4 a = ((const float4*)(base + (size_t)ss * 1024))[0];
    m0.x = fmaxf(m0.x, a.x); m0.y = fmaxf(m0.y, a.y);
    m0.z = fmaxf(m0.z, a.z); m0.w = fmaxf(m0.w, a.w);
  }
  float4* o = (float4*)(partial + ((size_t)(bx * 32 + sg)) * 1024 + t * 4);
  o[0] = m0;
}

// reduce2: out[b][l] = max(-1, max over 32 partials)
__global__ void __launch_bounds__(256) reduce2_kernel(
    const float* __restrict__ partial, float* __restrict__ out) {
  int idx = blockIdx.x * 256 + threadIdx.x;   // 0 .. 26623
  if (idx >= 26 * 1024) return;
  int bx = idx >> 10;
  int e  = idx & 1023;
  int b  = e >> 3;
  int ll = e & 7;
  int l  = bx * 8 + ll;
  if (l >= 200) return;
  float m = -1.0f;
  const float* p = partial + (size_t)(bx * 32) * 1024 + e;
  for (int c = 0; c < 32; ++c) m = fmaxf(m, p[(size_t)c * 1024]);
  out[b * 200 + l] = m;
}

// Brute-force fp32 fallback (only if ws_size is too small): one block per (b,l).
__global__ void __launch_bounds__(256) fallback_kernel(
    const float* __restrict__ embed, const float* __restrict__ label,
    float* __restrict__ out) {
  int b = blockIdx.x, l = blockIdx.y, t = threadIdx.x;
  float m = -1.0f;
  for (int p = t; p < 2048; p += 256) {
    int s = p >> 3, v = p & 7;
    const float* e = embed + (size_t)(s * 128 + b) * 768;
    const float* q = label + (size_t)(l * 8 + v) * 768;
    float dot = 0.f, ne = 0.f, nl = 0.f;
    for (int d = 0; d < 768; ++d) {
      float x = e[d], y = q[d];
      dot += x * y; ne += x * x; nl += y * y;
    }
    m = fmaxf(m, dot / fmaxf(sqrtf(ne) * sqrtf(nl), 1e-8f));
  }
  for (int off = 1; off < 64; off <<= 1) m = fmaxf(m, __shfl_xor(m, off));
  __shared__ float wmax[4];
  if ((t & 63) == 0) wmax[t >> 6] = m;
  __syncthreads();
  if (t == 0)
    out[b * 200 + l] = fmaxf(fmaxf(wmax[0], wmax[1]), fmaxf(wmax[2], wmax[3]));
}

extern "C" void kernel_launch(void* const* d_in, const int* in_sizes, int n_in,
                              void* d_out, int out_size, void* d_ws, size_t ws_size,
                              hipStream_t stream) {
  const float* embed = (const float*)d_in[0];   // [256,128,768]
  const float* label = (const float*)d_in[1];   // [200,8,768]
  float* out = (float*)d_out;                   // [128,200]

  const size_t szA = (size_t)32768 * 768 * 2;        // 50,331,648
  const size_t szB = (size_t)1664 * 768 * 2;         //  2,555,904
  const size_t szS = (size_t)26 * 256 * 1024 * 4;    // 27,262,976
  const size_t szP = (size_t)26 * 32 * 1024 * 4;     //  3,407,872

  if (ws_size < szA + szB + szS + szP) {
    dim3 g(128, 200);
    fallback_kernel<<<g, 256, 0, stream>>>(embed, label, out);
    return;
  }

  unsigned short* Ap = (unsigned short*)d_ws;
  unsigned short* Bp = (unsigned short*)((char*)d_ws + szA);
  float* scratch     = (float*)((char*)d_ws + szA + szB);
  float* partial     = (float*)((char*)d_ws + szA + szB + szS);

  normalize_all<<<8608, 256, 0, stream>>>(embed, label, Ap, Bp);
  gemm_store_kernel<<<6656, 256, 0, stream>>>(Ap, Bp, scratch);
  dim3 r1(26, 32);
  reduce1_kernel<<<r1, 256, 0, stream>>>(scratch, partial);
  reduce2_kernel<<<104, 256, 0, stream>>>(partial, out);
}